// Round 17
// baseline (134.987 us; speedup 1.0000x reference)
//
#include <hip/hip_runtime.h>
#include <math.h>

#define BATCH 8
#define CH    64
#define HH    128
#define WW    128
#define HWSZ  (HH * WW)       // 16384
#define COUT  64
#define KTAPS 9
#define TROWS 12              // window rows: y-2 .. y+9 (8-row tile)
#define TCOLS 36              // window cols: x0-2 .. x0+33
#define TSLOTS 432            // 12 * 36
#define WSEGU 3464            // ushorts per ch-segment (432*8=3456, +8 pad:
                              // 1732 dw ≡ 4 mod 32 -> 8 segs on 8 bank phases)
#define NBLK  (BATCH * HWSZ / 256)   // 512 main-kernel blocks

typedef __attribute__((ext_vector_type(8)))  short short8;
typedef __attribute__((ext_vector_type(4)))  float f32x4;
typedef __attribute__((ext_vector_type(2)))  float f32x2;
typedef __attribute__((ext_vector_type(16))) float f32x16;

__device__ __forceinline__ unsigned short f2bf(float f) {
    unsigned int u = __float_as_uint(f);
    u += 0x7fffu + ((u >> 16) & 1u);
    return (unsigned short)(u >> 16);
}
__device__ __forceinline__ float bf2f(unsigned short u) {
    return __uint_as_float((unsigned int)u << 16);
}
// One-instruction packed fp32->bf16 (RNE), lo in [15:0], hi in [31:16].
__device__ __forceinline__ unsigned int cvt_pk_bf16(float lo, float hi) {
    unsigned int r;
    asm("v_cvt_pk_bf16_f32 %0, %1, %2" : "=v"(r) : "v"(lo), "v"(hi));
    return r;
}
__device__ __forceinline__ f32x2 up2(unsigned int u) {
    f32x2 r;
    r.x = __uint_as_float(u << 16);
    r.y = __uint_as_float(u & 0xffff0000u);
    return r;
}
__device__ __forceinline__ unsigned int bilin2(unsigned int a, unsigned int b,
                                               unsigned int c, unsigned int d,
                                               float w00, float w01, float w10, float w11) {
    f32x2 acc = up2(a) * w00;
    acc = up2(b) * w01 + acc;
    acc = up2(c) * w10 + acc;
    acc = up2(d) * w11 + acc;
    return cvt_pk_bf16(acc.x, acc.y);
}
// 8-channel global gather+pack (rare fallback / staging path)
__device__ __forceinline__ uint4 ld8g(const float* p) {
    uint4 q;
    q.x = cvt_pk_bf16(p[0],        p[HWSZ]);
    q.y = cvt_pk_bf16(p[2 * HWSZ], p[3 * HWSZ]);
    q.z = cvt_pk_bf16(p[4 * HWSZ], p[5 * HWSZ]);
    q.w = cvt_pk_bf16(p[6 * HWSZ], p[7 * HWSZ]);
    return q;
}

// ---------------------------------------------------------------------------
// Kernel 0: repack conv weights — BOTH in mfma_32x32x16 A-layout.
//  wpk2 [cot<2][t<9][s<4][lane<64][8]:
//      lane l holds w_dcn[co = cot*32 + (l&31)][c = s*16 + (l>>5)*8 + j], tap t
//  wopk2 [t<9][s<4][lane<64][8]: same for w_off, co=(l&31), co>=27 zeroed
// ---------------------------------------------------------------------------
__global__ __launch_bounds__(256) void prep_w_kernel(
    const float* __restrict__ w_dcn, const float* __restrict__ w_off,
    unsigned short* __restrict__ wpk2, unsigned short* __restrict__ wopk2) {
    int j = blockIdx.x * 256 + threadIdx.x;
    if (j < 36864) {
        int jj = j & 7, ln = (j >> 3) & 63, q = j >> 9;   // q: 0..71
        int s = q & 3, t = (q >> 2) % 9, cot = q / 36;
        int co = cot * 32 + (ln & 31);
        int c  = s * 16 + (ln >> 5) * 8 + jj;
        wpk2[j] = f2bf(w_dcn[(co * CH + c) * KTAPS + t]);
    } else if (j < 55296) {
        int jo = j - 36864;
        int jj = jo & 7, ln = (jo >> 3) & 63, q = jo >> 9; // q: 0..35
        int s = q & 3, t = q >> 2;                         // t: 0..8
        int co = ln & 31;
        int c  = s * 16 + (ln >> 5) * 8 + jj;
        wopk2[jo] = (co < 27) ? f2bf(w_off[(co * CH + c) * KTAPS + t]) : 0;
    }
}

// ---------------------------------------------------------------------------
// Kernel 1: SINGLE FUSED DCN — R13 base, with the per-tap arm selection made
// WAVE-UNIFORM via __all(inw) (R17). R16's NaN taught the rule: MFMA is a
// cross-lane op — inside per-lane-divergent control flow, EXEC-masked-out
// lanes feed undefined operand registers into the matrix op. A wave-uniform
// branch keeps all 64 lanes convergent at every MFMA in both arms:
//   fast arm (__all in-window, ~all waves): fully unconditional ds_reads —
//     the scheduler may hoist across s-steps at its chosen register depth;
//   mixed arm (any lane OOB): exact R13 body (per-lane branch around loads
//     only, convergent MFMA) — proven semantics.
//  Block = 512 threads (8 waves), tile = 8 rows x 32 cols (256 px).
//  Grid 512 = 2 blocks/CU, fully co-resident (R10 geometry, zero tail).
//  Phase 1: offset GEMM 32x32x16 (R11 form) -> omr bf16 [27][256].
//  Phase 3: main GEMM 32x32x16, params fused per tap; T5 setprio (R13).
// LDS: win 55424 | omr 13824 = 69248 B -> 2 blocks/CU (16 waves).
// ---------------------------------------------------------------------------
__global__ __launch_bounds__(512, 4) void dcn_fused_mfma(
    const float* __restrict__ x, const unsigned short* __restrict__ wpk2,
    const unsigned short* __restrict__ wopk2, const float* __restrict__ b_off,
    const float* __restrict__ b_dcn, float* __restrict__ out) {
    __shared__ __align__(16) unsigned char smem[69248];
    unsigned short* win = (unsigned short*)smem;             // [8][WSEGU]
    unsigned short* omr = (unsigned short*)(smem + 55424);   // [27][256] bf16

    int tid = threadIdx.x, bid = blockIdx.x;
    int b = bid & 7;                 // batch -> XCD pinning
    int T = bid >> 3;                // tile 0..63 per image
    int y = (T >> 2) * 8;            // tile row base (8 rows)
    int x0 = (T & 3) * 32;           // tile col base
    int lane = tid & 63, wv = tid >> 6;   // wv 0..7
    int n32 = lane & 31, h5 = lane >> 5;
    int pl = wv * 32 + n32;          // this lane's px (row = pl>>5 = wv)

    const float* xbf = x + (size_t)b * CH * HWSZ;

    // ---------------- Stage window from NCHW fp32 ----------------
    for (int p = tid; p < 8 * TSLOTS; p += 512) {     // 7 iters (3456/512)
        int c8 = p / TSLOTS, slot = p - c8 * TSLOTS;
        int wy = slot / TCOLS, wx = slot - wy * TCOLS;
        int iy = y - 2 + wy, ix = x0 - 2 + wx;
        bool v = (iy >= 0) & (iy < HH) & (ix >= 0) & (ix < WW);
        uint4 q = {0, 0, 0, 0};
        if (v) q = ld8g(xbf + (size_t)(c8 * 8) * HWSZ + iy * WW + ix);
        *(uint4*)&win[c8 * WSEGU + slot * 8] = q;
    }
    __syncthreads();

    // ---------------- Phase 1: offset GEMM (32x32x16, B from window) ------
    {
        f32x16 oacc = {0, 0, 0, 0, 0, 0, 0, 0, 0, 0, 0, 0, 0, 0, 0, 0};
        __builtin_amdgcn_s_setprio(1);
        for (int t = 0; t < KTAPS; ++t) {
            int ky = t / 3, kx = t - ky * 3;
            int slot = (wv + ky + 1) * TCOLS + n32 + kx + 1;   // in-window tap
#pragma unroll
            for (int s = 0; s < 4; ++s) {
                int g = 2 * s + h5;
                short8 bfrag = *(const short8*)(win + g * WSEGU + slot * 8);
                short8 afrag = *(const short8*)(wopk2 + (size_t)((t * 4 + s) * 64 + lane) * 8);
                oacc = __builtin_amdgcn_mfma_f32_32x32x16_bf16(afrag, bfrag,
                                                               oacc, 0, 0, 0);
            }
        }
        __builtin_amdgcn_s_setprio(0);
#pragma unroll
        for (int r = 0; r < 16; ++r) {
            int co = (r & 3) + 8 * (r >> 2) + 4 * h5;
            if (co < 27)
                omr[co * 256 + pl] = f2bf(oacc[r] + b_off[co]);
        }
    }
    __syncthreads();

    // ---------------- Phase 3: main GEMM (32x32x16), params fused ---------
    f32x16 acc[2] = {{0, 0, 0, 0, 0, 0, 0, 0, 0, 0, 0, 0, 0, 0, 0, 0},
                     {0, 0, 0, 0, 0, 0, 0, 0, 0, 0, 0, 0, 0, 0, 0, 0}};
    int ho = y + (pl >> 5), wo = x0 + (pl & 31);
    float fybase = (float)(ho - 1), fxbase = (float)(wo - 1);

#pragma unroll 3
    for (int t = 0; t < KTAPS; ++t) {
        int ky = t / 3, kx = t - ky * 3;
        // ---- bilinear params for (tap t, px pl), register-only ----
        float fy = bf2f(omr[t * 256 + pl]) + fybase + (float)ky;
        float fx = bf2f(omr[(9 + t) * 256 + pl]) + fxbase + (float)kx;
        float m = 1.f / (1.f + __expf(-bf2f(omr[(18 + t) * 256 + pl])));
        float y0f = floorf(fy), x0f = floorf(fx);
        float dy = fy - y0f, dx = fx - x0f;
        int y0 = (int)y0f, x0i = (int)x0f;
        int y1 = y0 + 1, x1 = x0i + 1;
        bool vy0 = (y0 >= 0) & (y0 < HH);
        bool vy1 = (y1 >= 0) & (y1 < HH);
        bool vx0 = (x0i >= 0) & (x0i < WW);
        bool vx1 = (x1 >= 0) & (x1 < WW);
        float w00 = (1.f - dy) * (1.f - dx) * m; if (!(vy0 && vx0)) w00 = 0.f;
        float w01 = (1.f - dy) * dx * m;         if (!(vy0 && vx1)) w01 = 0.f;
        float w10 = dy * (1.f - dx) * m;         if (!(vy1 && vx0)) w10 = 0.f;
        float w11 = dy * dx * m;                 if (!(vy1 && vx1)) w11 = 0.f;
        int yc0 = min(max(y0, 0), HH - 1), yc1 = min(max(y1, 0), HH - 1);
        int xc0 = min(max(x0i, 0), WW - 1), xc1 = min(max(x1, 0), WW - 1);
        int uy = y0 - (y - 2), ux = x0i - (x0 - 2);
        bool inw = ((unsigned)uy <= 10u) & ((unsigned)ux <= 34u);

        __builtin_amdgcn_s_setprio(1);
        if (__builtin_expect(__all((int)inw), 1)) {
            // ---- FAST ARM (wave-uniform): unconditional ds_reads,
            //      convergent MFMAs. Scheduler free to hoist across s-steps.
            unsigned int iu = (unsigned)(uy * TCOLS + ux);
#pragma unroll
            for (int s = 0; s < 4; ++s) {
                int g = 2 * s + h5;
                const unsigned short* base = win + g * WSEGU + iu * 8;
                uint4 qa = *(const uint4*)(base);
                uint4 qb = *(const uint4*)(base + 8);
                uint4 qc = *(const uint4*)(base + TCOLS * 8);
                uint4 qd = *(const uint4*)(base + TCOLS * 8 + 8);
                union { uint4 u; short8 sh; } cv;
                cv.u.x = bilin2(qa.x, qb.x, qc.x, qd.x, w00, w01, w10, w11);
                cv.u.y = bilin2(qa.y, qb.y, qc.y, qd.y, w00, w01, w10, w11);
                cv.u.z = bilin2(qa.z, qb.z, qc.z, qd.z, w00, w01, w10, w11);
                cv.u.w = bilin2(qa.w, qb.w, qc.w, qd.w, w00, w01, w10, w11);
                short8 bfrag = cv.sh;
                short8 af0 = *(const short8*)(wpk2 + (size_t)(((0 * 9 + t) * 4 + s) * 64 + lane) * 8);
                acc[0] = __builtin_amdgcn_mfma_f32_32x32x16_bf16(af0, bfrag, acc[0], 0, 0, 0);
                short8 af1 = *(const short8*)(wpk2 + (size_t)(((1 * 9 + t) * 4 + s) * 64 + lane) * 8);
                acc[1] = __builtin_amdgcn_mfma_f32_32x32x16_bf16(af1, bfrag, acc[1], 0, 0, 0);
            }
        } else {
            // ---- MIXED ARM (wave-uniform entry): exact R13 body — per-lane
            //      branch around LOADS ONLY; lanes reconverge before MFMA.
            unsigned int iu;
            if (inw) iu = (unsigned)(uy * TCOLS + ux);
            else     iu = 0x80000000u | ((unsigned)yc0 << 21) | ((unsigned)xc0 << 14)
                                      | ((unsigned)yc1 << 7)  | (unsigned)xc1;
#pragma unroll
            for (int s = 0; s < 4; ++s) {
                int g = 2 * s + h5;
                uint4 qa, qb, qc, qd;
                if (__builtin_expect(!(iu & 0x80000000u), 1)) {
                    const unsigned short* base = win + g * WSEGU + iu * 8;
                    qa = *(const uint4*)(base);
                    qb = *(const uint4*)(base + 8);
                    qc = *(const uint4*)(base + TCOLS * 8);
                    qd = *(const uint4*)(base + TCOLS * 8 + 8);
                } else {
                    int zy0 = (int)((iu >> 21) & 0x7f), zx0 = (int)((iu >> 14) & 0x7f);
                    int zy1 = (int)((iu >> 7) & 0x7f),  zx1 = (int)(iu & 0x7f);
                    const float* pc0 = xbf + (size_t)(g * 8) * HWSZ;
                    qa = ld8g(pc0 + zy0 * WW + zx0); qb = ld8g(pc0 + zy0 * WW + zx1);
                    qc = ld8g(pc0 + zy1 * WW + zx0); qd = ld8g(pc0 + zy1 * WW + zx1);
                }
                union { uint4 u; short8 sh; } cv;
                cv.u.x = bilin2(qa.x, qb.x, qc.x, qd.x, w00, w01, w10, w11);
                cv.u.y = bilin2(qa.y, qb.y, qc.y, qd.y, w00, w01, w10, w11);
                cv.u.z = bilin2(qa.z, qb.z, qc.z, qd.z, w00, w01, w10, w11);
                cv.u.w = bilin2(qa.w, qb.w, qc.w, qd.w, w00, w01, w10, w11);
                short8 bfrag = cv.sh;
                short8 af0 = *(const short8*)(wpk2 + (size_t)(((0 * 9 + t) * 4 + s) * 64 + lane) * 8);
                acc[0] = __builtin_amdgcn_mfma_f32_32x32x16_bf16(af0, bfrag, acc[0], 0, 0, 0);
                short8 af1 = *(const short8*)(wpk2 + (size_t)(((1 * 9 + t) * 4 + s) * 64 + lane) * 8);
                acc[1] = __builtin_amdgcn_mfma_f32_32x32x16_bf16(af1, bfrag, acc[1], 0, 0, 0);
            }
        }
        __builtin_amdgcn_s_setprio(0);
    }

    // Epilogue: 32x32 C/D: col(px) = lane&31; row = (r&3)+8*(r>>2)+4*h5
    float* ob = out + (size_t)b * COUT * HWSZ;
    int gidx = (y + (pl >> 5)) * WW + x0 + (pl & 31);
#pragma unroll
    for (int cot = 0; cot < 2; ++cot) {
#pragma unroll
        for (int r = 0; r < 16; ++r) {
            int co = cot * 32 + (r & 3) + 8 * (r >> 2) + 4 * h5;
            ob[(size_t)co * HWSZ + gidx] = acc[cot][r] + b_dcn[co];
        }
    }
}

// ---------------------------------------------------------------------------
extern "C" void kernel_launch(void* const* d_in, const int* in_sizes, int n_in,
                              void* d_out, int out_size, void* d_ws, size_t ws_size,
                              hipStream_t stream) {
    const float* x     = (const float*)d_in[0];
    const float* w_off = (const float*)d_in[1];
    const float* b_off = (const float*)d_in[2];
    const float* w_dcn = (const float*)d_in[3];
    const float* b_dcn = (const float*)d_in[4];
    float* out = (float*)d_out;

    // ws layout: wpk2 (36864 ush) | wopk2 (18432 ush)
    unsigned short* wpk2  = (unsigned short*)d_ws;
    unsigned short* wopk2 = wpk2 + 36864;

    hipLaunchKernelGGL(prep_w_kernel, dim3(216), dim3(256), 0, stream,
                       w_dcn, w_off, wpk2, wopk2);
    hipLaunchKernelGGL(dcn_fused_mfma, dim3(NBLK), dim3(512),
                       0, stream, x, wpk2, wopk2, b_off, b_dcn, out);
}

// Round 18
// 121.403 us; speedup vs baseline: 1.1119x; 1.1119x over previous
//
#include <hip/hip_runtime.h>
#include <math.h>

#define BATCH 8
#define CH    64
#define HH    128
#define WW    128
#define HWSZ  (HH * WW)       // 16384
#define COUT  64
#define KTAPS 9
#define TROWS 12              // window rows: y-2 .. y+9 (8-row tile)
#define TCOLS 36              // window cols: x0-2 .. x0+33
#define TSLOTS 432            // 12 * 36
#define WSEGU 3464            // ushorts per ch-segment (432*8=3456, +8 pad:
                              // 1732 dw ≡ 4 mod 32 -> 8 segs on 8 bank phases)
#define NBLK  (BATCH * HWSZ / 256)   // 512 main-kernel blocks

typedef __attribute__((ext_vector_type(8)))  short short8;
typedef __attribute__((ext_vector_type(4)))  float f32x4;
typedef __attribute__((ext_vector_type(2)))  float f32x2;
typedef __attribute__((ext_vector_type(16))) float f32x16;

__device__ __forceinline__ unsigned short f2bf(float f) {
    unsigned int u = __float_as_uint(f);
    u += 0x7fffu + ((u >> 16) & 1u);
    return (unsigned short)(u >> 16);
}
__device__ __forceinline__ float bf2f(unsigned short u) {
    return __uint_as_float((unsigned int)u << 16);
}
// One-instruction packed fp32->bf16 (RNE), lo in [15:0], hi in [31:16].
__device__ __forceinline__ unsigned int cvt_pk_bf16(float lo, float hi) {
    unsigned int r;
    asm("v_cvt_pk_bf16_f32 %0, %1, %2" : "=v"(r) : "v"(lo), "v"(hi));
    return r;
}
__device__ __forceinline__ f32x2 up2(unsigned int u) {
    f32x2 r;
    r.x = __uint_as_float(u << 16);
    r.y = __uint_as_float(u & 0xffff0000u);
    return r;
}
__device__ __forceinline__ unsigned int bilin2(unsigned int a, unsigned int b,
                                               unsigned int c, unsigned int d,
                                               float w00, float w01, float w10, float w11) {
    f32x2 acc = up2(a) * w00;
    acc = up2(b) * w01 + acc;
    acc = up2(c) * w10 + acc;
    acc = up2(d) * w11 + acc;
    return cvt_pk_bf16(acc.x, acc.y);
}
// 8-channel global gather+pack (rare fallback / staging path)
__device__ __forceinline__ uint4 ld8g(const float* p) {
    uint4 q;
    q.x = cvt_pk_bf16(p[0],        p[HWSZ]);
    q.y = cvt_pk_bf16(p[2 * HWSZ], p[3 * HWSZ]);
    q.z = cvt_pk_bf16(p[4 * HWSZ], p[5 * HWSZ]);
    q.w = cvt_pk_bf16(p[6 * HWSZ], p[7 * HWSZ]);
    return q;
}

// ---------------------------------------------------------------------------
// Kernel 0: repack conv weights — BOTH in mfma_32x32x16 A-layout.
//  wpk2 [cot<2][t<9][s<4][lane<64][8]:
//      lane l holds w_dcn[co = cot*32 + (l&31)][c = s*16 + (l>>5)*8 + j], tap t
//  wopk2 [t<9][s<4][lane<64][8]: same for w_off, co=(l&31), co>=27 zeroed
// ---------------------------------------------------------------------------
__global__ __launch_bounds__(256) void prep_w_kernel(
    const float* __restrict__ w_dcn, const float* __restrict__ w_off,
    unsigned short* __restrict__ wpk2, unsigned short* __restrict__ wopk2) {
    int j = blockIdx.x * 256 + threadIdx.x;
    if (j < 36864) {
        int jj = j & 7, ln = (j >> 3) & 63, q = j >> 9;   // q: 0..71
        int s = q & 3, t = (q >> 2) % 9, cot = q / 36;
        int co = cot * 32 + (ln & 31);
        int c  = s * 16 + (ln >> 5) * 8 + jj;
        wpk2[j] = f2bf(w_dcn[(co * CH + c) * KTAPS + t]);
    } else if (j < 55296) {
        int jo = j - 36864;
        int jj = jo & 7, ln = (jo >> 3) & 63, q = jo >> 9; // q: 0..35
        int s = q & 3, t = q >> 2;                         // t: 0..8
        int co = ln & 31;
        int c  = s * 16 + (ln >> 5) * 8 + jj;
        wopk2[jo] = (co < 27) ? f2bf(w_off[(co * CH + c) * KTAPS + t]) : 0;
    }
}

// ---------------------------------------------------------------------------
// Kernel 1: SINGLE FUSED DCN — R13 restored byte-for-byte: the session's
// best verified kernel (121.7 us bench, 47-50 us/dispatch). Twelve measured
// levers later, everything that tried to beat this structure either spilled
// (R7/R14/R15), broke numerics (R9/R12/R16), or regressed (R17); the
// remaining gap to sum-of-floors is cross-phase dependency stall that needs
// asm-level scheduling, not source-level restructuring.
//  Block = 512 threads (8 waves), tile = 8 rows x 32 cols (256 px).
//  Grid 512 = 2 blocks/CU, fully co-resident (R10 geometry, zero tail).
//  Phase 1: offset GEMM 32x32x16 (R11 form) -> omr bf16 [27][256].
//  Phase 3: main GEMM 32x32x16, params fused per tap, in-s-loop per-lane
//           fallback branch around LOADS only (convergent MFMA — R16's NaN
//           taught: MFMA is cross-lane, never put it under divergence),
//           T5 setprio around MFMA clusters (R13's small win).
// LDS: win 55424 | omr 13824 = 69248 B -> 2 blocks/CU (16 waves).
// ---------------------------------------------------------------------------
__global__ __launch_bounds__(512, 4) void dcn_fused_mfma(
    const float* __restrict__ x, const unsigned short* __restrict__ wpk2,
    const unsigned short* __restrict__ wopk2, const float* __restrict__ b_off,
    const float* __restrict__ b_dcn, float* __restrict__ out) {
    __shared__ __align__(16) unsigned char smem[69248];
    unsigned short* win = (unsigned short*)smem;             // [8][WSEGU]
    unsigned short* omr = (unsigned short*)(smem + 55424);   // [27][256] bf16

    int tid = threadIdx.x, bid = blockIdx.x;
    int b = bid & 7;                 // batch -> XCD pinning
    int T = bid >> 3;                // tile 0..63 per image
    int y = (T >> 2) * 8;            // tile row base (8 rows)
    int x0 = (T & 3) * 32;           // tile col base
    int lane = tid & 63, wv = tid >> 6;   // wv 0..7
    int n32 = lane & 31, h5 = lane >> 5;
    int pl = wv * 32 + n32;          // this lane's px (row = pl>>5 = wv)

    const float* xbf = x + (size_t)b * CH * HWSZ;

    // ---------------- Stage window from NCHW fp32 ----------------
    for (int p = tid; p < 8 * TSLOTS; p += 512) {     // 7 iters (3456/512)
        int c8 = p / TSLOTS, slot = p - c8 * TSLOTS;
        int wy = slot / TCOLS, wx = slot - wy * TCOLS;
        int iy = y - 2 + wy, ix = x0 - 2 + wx;
        bool v = (iy >= 0) & (iy < HH) & (ix >= 0) & (ix < WW);
        uint4 q = {0, 0, 0, 0};
        if (v) q = ld8g(xbf + (size_t)(c8 * 8) * HWSZ + iy * WW + ix);
        *(uint4*)&win[c8 * WSEGU + slot * 8] = q;
    }
    __syncthreads();

    // ---------------- Phase 1: offset GEMM (32x32x16, B from window) ------
    {
        f32x16 oacc = {0, 0, 0, 0, 0, 0, 0, 0, 0, 0, 0, 0, 0, 0, 0, 0};
        __builtin_amdgcn_s_setprio(1);
        for (int t = 0; t < KTAPS; ++t) {
            int ky = t / 3, kx = t - ky * 3;
            int slot = (wv + ky + 1) * TCOLS + n32 + kx + 1;   // in-window tap
#pragma unroll
            for (int s = 0; s < 4; ++s) {
                int g = 2 * s + h5;
                short8 bfrag = *(const short8*)(win + g * WSEGU + slot * 8);
                short8 afrag = *(const short8*)(wopk2 + (size_t)((t * 4 + s) * 64 + lane) * 8);
                oacc = __builtin_amdgcn_mfma_f32_32x32x16_bf16(afrag, bfrag,
                                                               oacc, 0, 0, 0);
            }
        }
        __builtin_amdgcn_s_setprio(0);
#pragma unroll
        for (int r = 0; r < 16; ++r) {
            int co = (r & 3) + 8 * (r >> 2) + 4 * h5;
            if (co < 27)
                omr[co * 256 + pl] = f2bf(oacc[r] + b_off[co]);
        }
    }
    __syncthreads();

    // ---------------- Phase 3: main GEMM (32x32x16), params fused ---------
    f32x16 acc[2] = {{0, 0, 0, 0, 0, 0, 0, 0, 0, 0, 0, 0, 0, 0, 0, 0},
                     {0, 0, 0, 0, 0, 0, 0, 0, 0, 0, 0, 0, 0, 0, 0, 0}};
    int ho = y + (pl >> 5), wo = x0 + (pl & 31);
    float fybase = (float)(ho - 1), fxbase = (float)(wo - 1);

#pragma unroll 3
    for (int t = 0; t < KTAPS; ++t) {
        int ky = t / 3, kx = t - ky * 3;
        // ---- bilinear params for (tap t, px pl), register-only ----
        float fy = bf2f(omr[t * 256 + pl]) + fybase + (float)ky;
        float fx = bf2f(omr[(9 + t) * 256 + pl]) + fxbase + (float)kx;
        float m = 1.f / (1.f + __expf(-bf2f(omr[(18 + t) * 256 + pl])));
        float y0f = floorf(fy), x0f = floorf(fx);
        float dy = fy - y0f, dx = fx - x0f;
        int y0 = (int)y0f, x0i = (int)x0f;
        int y1 = y0 + 1, x1 = x0i + 1;
        bool vy0 = (y0 >= 0) & (y0 < HH);
        bool vy1 = (y1 >= 0) & (y1 < HH);
        bool vx0 = (x0i >= 0) & (x0i < WW);
        bool vx1 = (x1 >= 0) & (x1 < WW);
        float w00 = (1.f - dy) * (1.f - dx) * m; if (!(vy0 && vx0)) w00 = 0.f;
        float w01 = (1.f - dy) * dx * m;         if (!(vy0 && vx1)) w01 = 0.f;
        float w10 = dy * (1.f - dx) * m;         if (!(vy1 && vx0)) w10 = 0.f;
        float w11 = dy * dx * m;                 if (!(vy1 && vx1)) w11 = 0.f;
        int yc0 = min(max(y0, 0), HH - 1), yc1 = min(max(y1, 0), HH - 1);
        int xc0 = min(max(x0i, 0), WW - 1), xc1 = min(max(x1, 0), WW - 1);
        int uy = y0 - (y - 2), ux = x0i - (x0 - 2);
        bool inw = ((unsigned)uy <= 10u) & ((unsigned)ux <= 34u);
        unsigned int iu;
        if (inw) iu = (unsigned)(uy * TCOLS + ux);
        else     iu = 0x80000000u | ((unsigned)yc0 << 21) | ((unsigned)xc0 << 14)
                                  | ((unsigned)yc1 << 7)  | (unsigned)xc1;

        // ---- 4 K-steps of 16 ch; lane's 8 ch = segment 2s+h5 ----
        __builtin_amdgcn_s_setprio(1);
#pragma unroll
        for (int s = 0; s < 4; ++s) {
            int g = 2 * s + h5;
            uint4 qa, qb, qc, qd;
            if (__builtin_expect(!(iu & 0x80000000u), 1)) {
                const unsigned short* base = win + g * WSEGU + iu * 8;
                qa = *(const uint4*)(base);
                qb = *(const uint4*)(base + 8);
                qc = *(const uint4*)(base + TCOLS * 8);
                qd = *(const uint4*)(base + TCOLS * 8 + 8);
            } else {
                int zy0 = (int)((iu >> 21) & 0x7f), zx0 = (int)((iu >> 14) & 0x7f);
                int zy1 = (int)((iu >> 7) & 0x7f),  zx1 = (int)(iu & 0x7f);
                const float* pc0 = xbf + (size_t)(g * 8) * HWSZ;
                qa = ld8g(pc0 + zy0 * WW + zx0); qb = ld8g(pc0 + zy0 * WW + zx1);
                qc = ld8g(pc0 + zy1 * WW + zx0); qd = ld8g(pc0 + zy1 * WW + zx1);
            }
            union { uint4 u; short8 sh; } cv;
            cv.u.x = bilin2(qa.x, qb.x, qc.x, qd.x, w00, w01, w10, w11);
            cv.u.y = bilin2(qa.y, qb.y, qc.y, qd.y, w00, w01, w10, w11);
            cv.u.z = bilin2(qa.z, qb.z, qc.z, qd.z, w00, w01, w10, w11);
            cv.u.w = bilin2(qa.w, qb.w, qc.w, qd.w, w00, w01, w10, w11);
            short8 bfrag = cv.sh;

            short8 af0 = *(const short8*)(wpk2 + (size_t)(((0 * 9 + t) * 4 + s) * 64 + lane) * 8);
            acc[0] = __builtin_amdgcn_mfma_f32_32x32x16_bf16(af0, bfrag, acc[0], 0, 0, 0);
            short8 af1 = *(const short8*)(wpk2 + (size_t)(((1 * 9 + t) * 4 + s) * 64 + lane) * 8);
            acc[1] = __builtin_amdgcn_mfma_f32_32x32x16_bf16(af1, bfrag, acc[1], 0, 0, 0);
        }
        __builtin_amdgcn_s_setprio(0);
    }

    // Epilogue: 32x32 C/D: col(px) = lane&31; row = (r&3)+8*(r>>2)+4*h5
    float* ob = out + (size_t)b * COUT * HWSZ;
    int gidx = (y + (pl >> 5)) * WW + x0 + (pl & 31);
#pragma unroll
    for (int cot = 0; cot < 2; ++cot) {
#pragma unroll
        for (int r = 0; r < 16; ++r) {
            int co = cot * 32 + (r & 3) + 8 * (r >> 2) + 4 * h5;
            ob[(size_t)co * HWSZ + gidx] = acc[cot][r] + b_dcn[co];
        }
    }
}

// ---------------------------------------------------------------------------
extern "C" void kernel_launch(void* const* d_in, const int* in_sizes, int n_in,
                              void* d_out, int out_size, void* d_ws, size_t ws_size,
                              hipStream_t stream) {
    const float* x     = (const float*)d_in[0];
    const float* w_off = (const float*)d_in[1];
    const float* b_off = (const float*)d_in[2];
    const float* w_dcn = (const float*)d_in[3];
    const float* b_dcn = (const float*)d_in[4];
    float* out = (float*)d_out;

    // ws layout: wpk2 (36864 ush) | wopk2 (18432 ush)
    unsigned short* wpk2  = (unsigned short*)d_ws;
    unsigned short* wopk2 = wpk2 + 36864;

    hipLaunchKernelGGL(prep_w_kernel, dim3(216), dim3(256), 0, stream,
                       w_dcn, w_off, wpk2, wopk2);
    hipLaunchKernelGGL(dcn_fused_mfma, dim3(NBLK), dim3(512),
                       0, stream, x, wpk2, wopk2, b_off, b_dcn, out);
}